// Round 4
// baseline (671.923 us; speedup 1.0000x reference)
//
#include <hip/hip_runtime.h>
#include <math.h>

#define NN 50000
#define NE 600000
#define ADIM 75
#define HID 128
#define NLAYERS 4
#define NGRAPHS 128
#define BN_EPS 1e-5f
#define NNP 50048   // NN padded to 128-node blocks (50048 = 391*128)
#define NB128 (NNP / 128)   // 391 node-blocks

typedef short bhalf8 __attribute__((ext_vector_type(8)));
typedef float floatx4 __attribute__((ext_vector_type(4)));

__device__ __forceinline__ float sigm(float v) { return 1.0f / (1.0f + __expf(-v)); }
__device__ __forceinline__ float tanh_f(float v) {
    return 1.0f - 2.0f / (__expf(2.0f * v) + 1.0f);
}

// fp32 -> bf16 with round-to-nearest-even
__device__ __forceinline__ unsigned short f2bf(float f) {
    unsigned u = __builtin_bit_cast(unsigned, f);
    u = (u + 0x7FFFu + ((u >> 16) & 1u)) >> 16;
    return (unsigned short)u;
}
__device__ __forceinline__ float bf2f(unsigned short h) {
    return __builtin_bit_cast(float, ((unsigned)h) << 16);
}

// async global->LDS, 16B per lane. LDS dest is wave-uniform base + lane*16;
// global src is per-lane (must already include +lane*16).
__device__ __forceinline__ void gl2lds16(const void* g, void* l) {
    __builtin_amdgcn_global_load_lds(
        (const __attribute__((address_space(1))) unsigned int*)g,
        (__attribute__((address_space(3))) unsigned int*)l, 16, 0, 0);
}

// ---------------------------------------------------------------------------
// nf [NN x 75] fp32 -> nfb [NNP x 96] bf16 (K zero-padded 75->96)
// ---------------------------------------------------------------------------
__global__ __launch_bounds__(256) void k_nfb(
    const float* __restrict__ nf, unsigned short* __restrict__ nfb)
{
    int e = blockIdx.x * 256 + threadIdx.x;      // (n, k4): 50000*24
    if (e >= NN * 24) return;
    int n = e / 24, k4 = e - n * 24;
    ushort4 o;
    int k = k4 * 4;
    o.x = (k + 0 < ADIM) ? f2bf(nf[(size_t)n * ADIM + k + 0]) : 0;
    o.y = (k + 1 < ADIM) ? f2bf(nf[(size_t)n * ADIM + k + 1]) : 0;
    o.z = (k + 2 < ADIM) ? f2bf(nf[(size_t)n * ADIM + k + 2]) : 0;
    o.w = (k + 3 < ADIM) ? f2bf(nf[(size_t)n * ADIM + k + 3]) : 0;
    ((ushort4*)nfb)[(size_t)n * 24 + k4] = o;
}

// ---------------------------------------------------------------------------
// embW [128 x 75] -> bf16 B-fragments, K padded to 96:
//   layout [tc(8)][kb(3)][quad(4)][n(16)][j(8)], elem = W[tc*16+n][kb*32+quad*8+j]
// ---------------------------------------------------------------------------
__global__ __launch_bounds__(256) void k_wfrag_emb(
    const float* __restrict__ W, unsigned short* __restrict__ web)
{
    int e = blockIdx.x * 256 + threadIdx.x;      // 0..12287
    int j = e & 7, n = (e >> 3) & 15, quad = (e >> 7) & 3;
    int kb = (e >> 9) % 3, tc = e / 1536;
    int row = tc * 16 + n;
    int kk = kb * 32 + quad * 8 + j;
    web[e] = (kk < ADIM) ? f2bf(W[row * ADIM + kk]) : 0;
}

// ---------------------------------------------------------------------------
// MFMA embedding: y = relu(nf @ embW^T + b), BN sums into slot 0.
// R19: 128 nodes/block (2 node-tiles per wave), grid 391 — R16-R18 showed
// per-block latency (~16 us) x block-rounds (~3) governs; 2x nodes/block
// puts the whole grid in one resident round and halves weight re-reads.
// ---------------------------------------------------------------------------
__global__ __launch_bounds__(256) void k_embed_m(
    const unsigned short* __restrict__ nfb, const unsigned short* __restrict__ web,
    const float* __restrict__ b, float* __restrict__ y,
    double* __restrict__ bnsum)
{
    __shared__ __align__(16) unsigned short wbe[12288];    // 24 KB emb B-frags
    __shared__ float sred[512], sred2[512];                // 4 KB BN partials
    const int t = threadIdx.x;
    const int wave = t >> 6, lane = t & 63;
    const int col = lane & 15, quad = (lane >> 4) & 3;
    const int node0 = blockIdx.x * 128;

    // stage web: 24576 B = 4 waves x 6 KB, identity copy
    {
        const char* gsrc = (const char*)web + wave * 6144 + lane * 16;
        char* ldst = (char*)wbe + wave * 6144;
#pragma unroll
        for (int i = 0; i < 6; i++)
            gl2lds16(gsrc + i * 1024, ldst + i * 1024);
    }

    const int an0 = node0 + wave * 32 + col;
    const int an1 = an0 + 16;
    bhalf8 afN0[3], afN1[3];
#pragma unroll
    for (int kb = 0; kb < 3; kb++) {
        afN0[kb] = *(const bhalf8*)&nfb[(size_t)an0 * 96 + kb * 32 + quad * 8];
        afN1[kb] = *(const bhalf8*)&nfb[(size_t)an1 * 96 + kb * 32 + quad * 8];
    }

    floatx4 acc0[8], acc1[8];
#pragma unroll
    for (int tc = 0; tc < 8; tc++) {
        float bv = b[tc * 16 + col];
        acc0[tc] = (floatx4){bv, bv, bv, bv};
        acc1[tc] = (floatx4){bv, bv, bv, bv};
    }
    __syncthreads();   // drains vmcnt -> wbe staged

#pragma unroll
    for (int tc = 0; tc < 8; tc++) {
        bhalf8 bfr[3];
#pragma unroll
        for (int kb = 0; kb < 3; kb++)
            bfr[kb] = *(const bhalf8*)&wbe[((tc * 3 + kb) * 64 + lane) * 8];
#pragma unroll
        for (int kb = 0; kb < 3; kb++) {
            acc0[tc] = __builtin_amdgcn_mfma_f32_16x16x32_bf16(afN0[kb], bfr[kb], acc0[tc], 0, 0, 0);
            acc1[tc] = __builtin_amdgcn_mfma_f32_16x16x32_bf16(afN1[kb], bfr[kb], acc1[tc], 0, 0, 0);
        }
    }

    // relu + direct y stores + register BN partials (both tiles)
    float ps[8], ps2[8];
#pragma unroll
    for (int tc = 0; tc < 8; tc++) {
        ps[tc] = 0.f; ps2[tc] = 0.f;
#pragma unroll
        for (int e = 0; e < 4; e++) {
            int nd0 = node0 + wave * 32 + quad * 4 + e;
            int nd1 = nd0 + 16;
            float v0 = fmaxf(acc0[tc][e], 0.0f);
            float v1 = fmaxf(acc1[tc][e], 0.0f);
            if (nd0 < NN) {
                y[(size_t)nd0 * HID + tc * 16 + col] = v0;
                ps[tc] += v0; ps2[tc] += v0 * v0;
            }
            if (nd1 < NN) {
                y[(size_t)nd1 * HID + tc * 16 + col] = v1;
                ps[tc] += v1; ps2[tc] += v1 * v1;
            }
        }
    }
#pragma unroll
    for (int tc = 0; tc < 8; tc++) {
        ps[tc]  += __shfl_xor(ps[tc], 16);  ps2[tc] += __shfl_xor(ps2[tc], 16);
        ps[tc]  += __shfl_xor(ps[tc], 32);  ps2[tc] += __shfl_xor(ps2[tc], 32);
    }
    if (quad == 0) {
#pragma unroll
        for (int tc = 0; tc < 8; tc++) {
            sred[wave * 128 + tc * 16 + col]  = ps[tc];
            sred2[wave * 128 + tc * 16 + col] = ps2[tc];
        }
    }
    __syncthreads();
    if (t < 128) {
        float s  = sred[t]  + sred[128 + t]  + sred[256 + t]  + sred[384 + t];
        float s2 = sred2[t] + sred2[128 + t] + sred2[256 + t] + sred2[384 + t];
        unsafeAtomicAdd(&bnsum[t], (double)s);
        unsafeAtomicAdd(&bnsum[128 + t], (double)s2);
    }
}

// ---------------------------------------------------------------------------
// Fused BN-finalize + BN-apply + bf16 mirror + attention projections.
// ---------------------------------------------------------------------------
__global__ __launch_bounds__(256) void k_bnx(
    const float* __restrict__ y, const double* __restrict__ bnsum,
    const float* __restrict__ g, const float* __restrict__ beta,
    const float* __restrict__ attW,
    unsigned short* __restrict__ xb,
    float* __restrict__ as_, float* __restrict__ ad_)
{
    const int t = threadIdx.x;
    const int n = blockIdx.x * 4 + (t >> 6);
    const int lane = t & 63;
    const int f0 = lane * 2;
    // per-thread BN scale/shift for features f0, f0+1
    double m0 = bnsum[f0] / (double)NN;
    double v0 = bnsum[128 + f0] / (double)NN - m0 * m0;
    double m1 = bnsum[f0 + 1] / (double)NN;
    double v1 = bnsum[128 + f0 + 1] / (double)NN - m1 * m1;
    float sc0 = g[f0] * rsqrtf((float)v0 + BN_EPS);
    float sc1 = g[f0 + 1] * rsqrtf((float)v1 + BN_EPS);
    float sh0 = beta[f0] - (float)m0 * sc0;
    float sh1 = beta[f0 + 1] - (float)m1 * sc1;

    float2 v = ((const float2*)y)[(size_t)n * 64 + lane];
    float2 xv;
    xv.x = v.x * sc0 + sh0;
    xv.y = v.y * sc1 + sh1;
    unsigned pk = (unsigned)f2bf(xv.x) | ((unsigned)f2bf(xv.y) << 16);
    ((unsigned*)xb)[(size_t)n * 64 + lane] = pk;
    float2 aws = ((const float2*)attW)[lane];
    float2 awd = ((const float2*)(attW + 128))[lane];
    float pas = xv.x * aws.x + xv.y * aws.y;
    float pad = xv.x * awd.x + xv.y * awd.y;
#pragma unroll
    for (int msk = 32; msk >= 1; msk >>= 1) {
        pas += __shfl_xor(pas, msk);
        pad += __shfl_xor(pad, msk);
    }
    if (lane == 0) { as_[n] = pas; ad_[n] = pad; }
}

// ---------------------------------------------------------------------------
// Combined-weight precompute: Wc[l] = Wih[l] @ Wm[l], bmih[l] = Wih[l] @ bm[l]
// ---------------------------------------------------------------------------
__global__ __launch_bounds__(128) void k_wc(
    const float* __restrict__ Wih, const float* __restrict__ Wm,
    const float* __restrict__ bm, float* __restrict__ Wc, float* __restrict__ bmih)
{
    __shared__ float sw[128];
    __shared__ float red[128];
    const int b = blockIdx.x;
    const int l = b / 384, r = b - l * 384;
    const int t = threadIdx.x;
    const float* wihrow = Wih + ((size_t)l * 384 + r) * 128;
    sw[t] = wihrow[t];
    __syncthreads();
    const float* wm = Wm + (size_t)l * 128 * 128;
    float acc = 0.f;
#pragma unroll 8
    for (int k = 0; k < 128; k++) acc += sw[k] * wm[k * 128 + t];
    Wc[((size_t)l * 384 + r) * 128 + t] = acc;
    red[t] = sw[t] * bm[l * 128 + t];
    __syncthreads();
#pragma unroll
    for (int off = 64; off >= 1; off >>= 1) {
        if (t < off) red[t] += red[t + off];
        __syncthreads();
    }
    if (t == 0) bmih[l * 384 + r] = red[0];
}

// ---------------------------------------------------------------------------
// Convert Wc (fp32) and Whh to bf16 in MFMA B-fragment order:
//   layout [gate(3)][tc(8)][kb(4)][quad(4)][n(16)][j(8)] per layer-matrix
// ---------------------------------------------------------------------------
__global__ __launch_bounds__(256) void k_frag(
    const float* __restrict__ Wc, const float* __restrict__ Whh,
    unsigned short* __restrict__ wcb, unsigned short* __restrict__ whhb)
{
    const int b = blockIdx.x;
    const int mat = b / 192;
    const int e = (b - mat * 192) * 256 + threadIdx.x;   // 0..49151
    const int l = mat >> 1, which = mat & 1;
    const float* src = which ? (Whh + (size_t)l * 49152) : (Wc + (size_t)l * 49152);
    unsigned short* dst = which ? (whhb + (size_t)l * 49152) : (wcb + (size_t)l * 49152);
    int j = e & 7, n = (e >> 3) & 15, quad = (e >> 7) & 3;
    int kb = (e >> 9) & 3, tc = (e >> 11) & 7, g = (e >> 14) & 3;
    int row = g * 128 + tc * 16 + n;
    int kk = kb * 32 + quad * 8 + j;
    dst[e] = f2bf(src[row * 128 + kk]);
}

// ---------------------------------------------------------------------------
// CSR build: histogram, 3-kernel device-wide scan, scatter
// ---------------------------------------------------------------------------
__global__ __launch_bounds__(256) void k_count(const int* __restrict__ dst, int* __restrict__ cnt)
{
    int e = blockIdx.x * 256 + threadIdx.x;
    if (e < NE) atomicAdd(&cnt[dst[e]], 1);
}

#define SCAN_B 512
#define SCAN_G 98          // 98*512 = 50176 >= 50000

__global__ __launch_bounds__(SCAN_B) void k_scan1(
    const int* __restrict__ cnt, int* __restrict__ rowptr, int* __restrict__ bsum)
{
    __shared__ int s[SCAN_B];
    const int t = threadIdx.x;
    const int i = blockIdx.x * SCAN_B + t;
    int v = (i < NN) ? cnt[i] : 0;
    s[t] = v;
    __syncthreads();
#pragma unroll
    for (int off = 1; off < SCAN_B; off <<= 1) {
        int u = (t >= off) ? s[t - off] : 0;
        __syncthreads();
        s[t] += u;
        __syncthreads();
    }
    if (i < NN) rowptr[i] = s[t] - v;        // local exclusive
    if (t == SCAN_B - 1) bsum[blockIdx.x] = s[t];
}

__global__ __launch_bounds__(128) void k_scan2(int* __restrict__ bsum, int* __restrict__ rowptr)
{
    __shared__ int s[128];
    const int t = threadIdx.x;
    int v = (t < SCAN_G) ? bsum[t] : 0;
    s[t] = v;
    __syncthreads();
#pragma unroll
    for (int off = 1; off < 128; off <<= 1) {
        int u = (t >= off) ? s[t - off] : 0;
        __syncthreads();
        s[t] += u;
        __syncthreads();
    }
    if (t < SCAN_G) bsum[t] = s[t] - v;      // exclusive offsets
    if (t == 127) rowptr[NN] = s[127];       // grand total (= NE)
}

__global__ __launch_bounds__(SCAN_B) void k_scan3(
    int* __restrict__ rowptr, const int* __restrict__ bsum, int* __restrict__ wptr)
{
    const int i = blockIdx.x * SCAN_B + threadIdx.x;
    if (i < NN) {
        int v = rowptr[i] + bsum[blockIdx.x];
        rowptr[i] = v;
        wptr[i] = v;
    }
}

__global__ __launch_bounds__(256) void k_scatter(
    const int* __restrict__ src, const int* __restrict__ dst,
    int* __restrict__ wptr, int* __restrict__ ssrc)
{
    int e = blockIdx.x * 256 + threadIdx.x;
    if (e < NE) {
        int d = dst[e];
        int pos = atomicAdd(&wptr[d], 1);
        ssrc[pos] = src[e];
    }
}

// ---------------------------------------------------------------------------
// Gather-aggregate, batched + id-PIPELINED. block 256 = 8 nodes x 32 lanes.
// ---------------------------------------------------------------------------
__global__ __launch_bounds__(256) void k_gather(
    const int* __restrict__ rowptr, const int* __restrict__ ssrc,
    const unsigned short* __restrict__ xb, const float* __restrict__ as_,
    const float* __restrict__ ad_, const float* __restrict__ attb, int l,
    unsigned short* __restrict__ aggxb, float* __restrict__ sumatt)
{
    const int t = threadIdx.x;
    const int n = blockIdx.x * 8 + (t >> 5);
    const int lane = t & 31;
    const int r0 = rowptr[n], r1 = rowptr[n + 1];
    const float adv = ad_[n] + attb[l];
    float4 acc = make_float4(0.f, 0.f, 0.f, 0.f);
    float satt = 0.f;

    int ids[8], ids2[8];
    if (r0 < r1) {
#pragma unroll
        for (int k = 0; k < 8; k++) {
            int idx = r0 + k; if (idx >= r1) idx = r1 - 1;
            ids[k] = ssrc[idx];
        }
    }
    for (int base = r0; base < r1; base += 8) {
        const int nxt = base + 8;
        if (nxt < r1) {
#pragma unroll
            for (int k = 0; k < 8; k++) {
                int idx = nxt + k; if (idx >= r1) idx = r1 - 1;
                ids2[k] = ssrc[idx];
            }
        }
        ushort4 v[8];
        float a[8];
#pragma unroll
        for (int k = 0; k < 8; k++) {
            v[k] = ((const ushort4*)xb)[(size_t)ids[k] * 32 + lane];
            a[k] = as_[ids[k]];
        }
#pragma unroll
        for (int k = 0; k < 8; k++) {
            if (base + k < r1) {
                float att = sigm(a[k] + adv);
                acc.x += bf2f(v[k].x) * att; acc.y += bf2f(v[k].y) * att;
                acc.z += bf2f(v[k].z) * att; acc.w += bf2f(v[k].w) * att;
                satt += att;
            }
        }
#pragma unroll
        for (int k = 0; k < 8; k++) ids[k] = ids2[k];
    }
    ushort4 o;
    o.x = f2bf(acc.x); o.y = f2bf(acc.y); o.z = f2bf(acc.z); o.w = f2bf(acc.w);
    ((ushort4*)aggxb)[(size_t)n * 32 + lane] = o;
    if (lane == 0) sumatt[n] = satt;
}

// ---------------------------------------------------------------------------
// MFMA GRU — R19: 128 nodes/block (2 node-tiles per wave), grid 391.
// R16-R18 post-mortem: dur invariant (~50 us) under schedule serialization,
// counted-vmcnt pipelining, and LDS/occupancy changes. Governing model:
// per-block latency-bound critical path (~16 us) x sequential block-rounds
// (782 blocks / ~1-resident/CU ~= 3 rounds). Fix: 2 A-tiles per wave ->
// grid 391 <= resident capacity (2 blocks/CU @ 36 KB LDS, ~230 VGPR) ->
// ONE round; each B-fragment ds_read feeds 2 MFMAs; weight L2 traffic /2.
// Watch: VGPR >= 256 + scratch = fail mode (then split afX liveness).
// R11/R13: do NOT force occupancy via launch_bounds/waves_per_eu.
// R8: do NOT split this grid along columns — A-traffic multiplies.
// ---------------------------------------------------------------------------
#define STAGE_W(SRC)                                                          \
    {                                                                         \
        const char* gsrc = (const char*)(SRC) + wave * 8192 + lane * 16;      \
        char* ldst = (char*)wbuf + wave * 8192;                               \
        _Pragma("unroll")                                                     \
        for (int i = 0; i < 8; i++)                                           \
            gl2lds16(gsrc + i * 1024, ldst + i * 1024);                       \
    }

#define MMGL2(AF0, AF1, ACC0, ACC1)                                           \
    _Pragma("unroll")                                                         \
    for (int tc = 0; tc < 8; tc++) {                                          \
        bhalf8 bfr[4];                                                        \
        _Pragma("unroll")                                                     \
        for (int kb = 0; kb < 4; kb++)                                        \
            bfr[kb] = *(const bhalf8*)&wbuf[((tc * 4 + kb) * 64 + lane) * 8]; \
        _Pragma("unroll")                                                     \
        for (int kb = 0; kb < 4; kb++) {                                      \
            ACC0[tc] = __builtin_amdgcn_mfma_f32_16x16x32_bf16(AF0[kb], bfr[kb], ACC0[tc], 0, 0, 0); \
            ACC1[tc] = __builtin_amdgcn_mfma_f32_16x16x32_bf16(AF1[kb], bfr[kb], ACC1[tc], 0, 0, 0); \
        }                                                                     \
    }

__global__ __launch_bounds__(256) void k_gru(
    const unsigned short* __restrict__ aggxb, const float* __restrict__ sumatt,
    const unsigned short* __restrict__ xb,
    const unsigned short* __restrict__ wcb, const float* __restrict__ bmih,
    const float* __restrict__ bih,
    const unsigned short* __restrict__ whhb, const float* __restrict__ bhh,
    float* __restrict__ y, double* __restrict__ bnsum)
{
    __shared__ __align__(16) unsigned short wbuf[16384];   // 32 KB weight stage
    __shared__ float sred[512], sred2[512];                // 4 KB BN partials
    const int t = threadIdx.x;
    const int wave = t >> 6, lane = t & 63;
    const int col = lane & 15, quad = (lane >> 4) & 3;
    const int node0 = blockIdx.x * 128;

    STAGE_W(wcb + 0 * 16384);    // issue gate-r Wc stage before A loads

    const int an0 = node0 + wave * 32 + col;
    const int an1 = an0 + 16;
    bhalf8 afA0[4], afA1[4], afX0[4], afX1[4];
#pragma unroll
    for (int kb = 0; kb < 4; kb++) {
        afA0[kb] = *(const bhalf8*)&aggxb[(size_t)an0 * HID + kb * 32 + quad * 8];
        afA1[kb] = *(const bhalf8*)&aggxb[(size_t)an1 * HID + kb * 32 + quad * 8];
        afX0[kb] = *(const bhalf8*)&xb[(size_t)an0 * HID + kb * 32 + quad * 8];
        afX1[kb] = *(const bhalf8*)&xb[(size_t)an1 * HID + kb * 32 + quad * 8];
    }
    float sa0[4], sa1[4];
#pragma unroll
    for (int e = 0; e < 4; e++) {
        sa0[e] = sumatt[node0 + wave * 32 + quad * 4 + e];
        sa1[e] = sumatt[node0 + wave * 32 + quad * 4 + e + 16];
    }

    floatx4 accR0[8], accR1[8], accN0[8], accN1[8];

    // ===== gate r: merged accumulator (gi+gh) =====
#pragma unroll
    for (int tc = 0; tc < 8; tc++) {
        int f = 0 * 128 + tc * 16 + col;
        float b0 = bih[f] + bhh[f], bm = bmih[f];
        accR0[tc] = (floatx4){b0 + sa0[0] * bm, b0 + sa0[1] * bm, b0 + sa0[2] * bm, b0 + sa0[3] * bm};
        accR1[tc] = (floatx4){b0 + sa1[0] * bm, b0 + sa1[1] * bm, b0 + sa1[2] * bm, b0 + sa1[3] * bm};
    }
    __syncthreads();                 // wcb[r] staged (drains vmcnt)
    MMGL2(afA0, afA1, accR0, accR1);
    __syncthreads();                 // all waves done reading
    STAGE_W(whhb + 0 * 16384);
    __syncthreads();
    MMGL2(afX0, afX1, accR0, accR1);
    __syncthreads();
    STAGE_W(whhb + 2 * 16384);       // prefetch gate-n Whh; sigm overlaps
#pragma unroll
    for (int tc = 0; tc < 8; tc++)
#pragma unroll
        for (int e = 0; e < 4; e++) {
            accR0[tc][e] = sigm(accR0[tc][e]);        // accR now holds r
            accR1[tc][e] = sigm(accR1[tc][e]);
        }

    // ===== gate n: acc = afX@Whh + bh; acc = r*acc + bi + sa*bm; acc += afA@Wc =====
#pragma unroll
    for (int tc = 0; tc < 8; tc++) {
        float bh = bhh[2 * 128 + tc * 16 + col];
        accN0[tc] = (floatx4){bh, bh, bh, bh};
        accN1[tc] = (floatx4){bh, bh, bh, bh};
    }
    __syncthreads();
    MMGL2(afX0, afX1, accN0, accN1);
    __syncthreads();
    STAGE_W(wcb + 2 * 16384);        // prefetch gate-n Wc; r-merge overlaps
#pragma unroll
    for (int tc = 0; tc < 8; tc++) {
        int f = 2 * 128 + tc * 16 + col;
        float bi = bih[f], bm = bmih[f];
#pragma unroll
        for (int e = 0; e < 4; e++) {
            accN0[tc][e] = accR0[tc][e] * accN0[tc][e] + bi + sa0[e] * bm;
            accN1[tc][e] = accR1[tc][e] * accN1[tc][e] + bi + sa1[e] * bm;
        }
    }
    __syncthreads();
    MMGL2(afA0, afA1, accN0, accN1);
    __syncthreads();
    STAGE_W(wcb + 1 * 16384);        // prefetch gate-z Wc; tanh overlaps
#pragma unroll
    for (int tc = 0; tc < 8; tc++)
#pragma unroll
        for (int e = 0; e < 4; e++) {
            accN0[tc][e] = tanh_f(accN0[tc][e]);      // accN now holds n
            accN1[tc][e] = tanh_f(accN1[tc][e]);
        }

    // ===== gate z: merged accumulator (reuse accR) =====
#pragma unroll
    for (int tc = 0; tc < 8; tc++) {
        int f = 1 * 128 + tc * 16 + col;
        float b0 = bih[f] + bhh[f], bm = bmih[f];
        accR0[tc] = (floatx4){b0 + sa0[0] * bm, b0 + sa0[1] * bm, b0 + sa0[2] * bm, b0 + sa0[3] * bm};
        accR1[tc] = (floatx4){b0 + sa1[0] * bm, b0 + sa1[1] * bm, b0 + sa1[2] * bm, b0 + sa1[3] * bm};
    }
    __syncthreads();
    MMGL2(afA0, afA1, accR0, accR1);
    __syncthreads();
    STAGE_W(whhb + 1 * 16384);
    __syncthreads();
    MMGL2(afX0, afX1, accR0, accR1);

    // ===== h = (1-z)*n + z*x; direct y stores; register BN partials =====
    float ps[8], ps2[8];
#pragma unroll
    for (int tc = 0; tc < 8; tc++) {
        ps[tc] = 0.f; ps2[tc] = 0.f;
#pragma unroll
        for (int e = 0; e < 4; e++) {
            int nd0 = node0 + wave * 32 + quad * 4 + e;
            int nd1 = nd0 + 16;
            float z0 = sigm(accR0[tc][e]);
            float z1 = sigm(accR1[tc][e]);
            float xv0 = bf2f(xb[(size_t)nd0 * HID + tc * 16 + col]);
            float xv1 = bf2f(xb[(size_t)nd1 * HID + tc * 16 + col]);
            float h0 = (1.0f - z0) * accN0[tc][e] + z0 * xv0;
            float h1 = (1.0f - z1) * accN1[tc][e] + z1 * xv1;
            if (nd0 < NN) {
                y[(size_t)nd0 * HID + tc * 16 + col] = h0;
                ps[tc] += h0; ps2[tc] += h0 * h0;
            }
            if (nd1 < NN) {
                y[(size_t)nd1 * HID + tc * 16 + col] = h1;
                ps[tc] += h1; ps2[tc] += h1 * h1;
            }
        }
    }
#pragma unroll
    for (int tc = 0; tc < 8; tc++) {
        ps[tc]  += __shfl_xor(ps[tc], 16);  ps2[tc] += __shfl_xor(ps2[tc], 16);
        ps[tc]  += __shfl_xor(ps[tc], 32);  ps2[tc] += __shfl_xor(ps2[tc], 32);
    }
    if (quad == 0) {
#pragma unroll
        for (int tc = 0; tc < 8; tc++) {
            sred[wave * 128 + tc * 16 + col]  = ps[tc];
            sred2[wave * 128 + tc * 16 + col] = ps2[tc];
        }
    }
    __syncthreads();
    if (t < 128) {
        float s  = sred[t]  + sred[128 + t]  + sred[256 + t]  + sred[384 + t];
        float s2 = sred2[t] + sred2[128 + t] + sred2[256 + t] + sred2[384 + t];
        unsafeAtomicAdd(&bnsum[t], (double)s);
        unsafeAtomicAdd(&bnsum[128 + t], (double)s2);
    }
}

// ---------------------------------------------------------------------------
// Segmented sum-pool over bf16 xb (batch_idx is SORTED)
// ---------------------------------------------------------------------------
__global__ __launch_bounds__(256) void k_pool(
    const unsigned short* __restrict__ xb, const int* __restrict__ batch,
    float* __restrict__ gr)
{
    __shared__ int sb[256];
    const int t = threadIdx.x;
    const int nb = blockIdx.x * 256;
    int ld = nb + t; if (ld >= NN) ld = NN - 1;
    sb[t] = batch[ld];
    __syncthreads();
    const int s = t >> 7, f = t & 127;
    float acc = 0.f; int cur = -1;
    for (int i = s; i < 256; i += 2) {
        int n = nb + i;
        if (n >= NN) break;
        int g = sb[i];
        if (g != cur) {
            if (cur >= 0) unsafeAtomicAdd(&gr[(size_t)cur * HID + f], acc);
            acc = 0.f; cur = g;
        }
        acc += bf2f(xb[(size_t)n * HID + f]);
    }
    if (cur >= 0) unsafeAtomicAdd(&gr[(size_t)cur * HID + f], acc);
}

// ---------------------------------------------------------------------------
// Readout: out[g] = relu(gr[g] @ W1^T + b1) @ W2^T + b2   (128 blocks x 64)
// ---------------------------------------------------------------------------
__global__ __launch_bounds__(64) void k_readout(
    const float* __restrict__ gr, const float* __restrict__ W1,
    const float* __restrict__ b1, const float* __restrict__ W2,
    const float* __restrict__ b2, float* __restrict__ out)
{
    const int g = blockIdx.x, j = threadIdx.x;
    float acc = b1[j];
    const float4* grow = (const float4*)&gr[g * HID];
    const float4* wrow = (const float4*)&W1[j * HID];
#pragma unroll
    for (int k4 = 0; k4 < 32; k4++) {
        float4 a = grow[k4], w = wrow[k4];
        acc += a.x * w.x + a.y * w.y + a.z * w.z + a.w * w.w;
    }
    float h = fmaxf(acc, 0.0f) * W2[j];
#pragma unroll
    for (int msk = 32; msk >= 1; msk >>= 1) h += __shfl_xor(h, msk);
    if (j == 0) out[g] = h + b2[0];
}

// ---------------------------------------------------------------------------
extern "C" void kernel_launch(void* const* d_in, const int* in_sizes, int n_in,
                              void* d_out, int out_size, void* d_ws, size_t ws_size,
                              hipStream_t stream)
{
    const float* nf    = (const float*)d_in[0];
    const int*   ei    = (const int*)d_in[1];
    const int*   batch = (const int*)d_in[2];
    const float* embW  = (const float*)d_in[3];
    const float* embb  = (const float*)d_in[4];
    const float* embg  = (const float*)d_in[5];
    const float* embbe = (const float*)d_in[6];
    const float* msgW  = (const float*)d_in[7];
    const float* msgb  = (const float*)d_in[8];
    const float* attW  = (const float*)d_in[9];
    const float* attb  = (const float*)d_in[10];
    const float* Wih   = (const float*)d_in[11];
    const float* bih   = (const float*)d_in[12];
    const float* Whh   = (const float*)d_in[13];
    const float* bhh   = (const float*)d_in[14];
    const float* bng   = (const float*)d_in[15];
    const float* bnb   = (const float*)d_in[16];
    const float* roW1  = (const float*)d_in[17];
    const float* rob1  = (const float*)d_in[18];
    const float* roW2  = (const float*)d_in[19];
    const float* rob2  = (const float*)d_in[20];
    const int* src = ei;
    const int* dst = ei + NE;
    float* out = (float*)d_out;

    // ---- workspace layout (all sections 16B-multiple) ----
    char* base = (char*)d_ws;
    const size_t NH = (size_t)NN * HID;      // 6.4M elements
    double* bnsum = (double*)base;           // 5 slots x 256 doubles = 10240 B
    float* y     = (float*)(base + 10240);   // pre-BN state
    unsigned short* xb    = (unsigned short*)(y + NH);   // bf16 node state
    unsigned short* aggxb = xb + NH;                     // bf16 gather output
    float* as_   = (float*)(aggxb + NH);
    float* ad_   = as_ + NN;
    float* sumatt= ad_ + NN;
    float* gr    = sumatt + NN;              // 128*128
    float* Wc    = gr + NGRAPHS * HID;       // 4*384*128 fp32
    float* bmih  = Wc + 4 * 384 * 128;       // 4*384
    int* rowptr  = (int*)(bmih + 4 * 384);   // NN+4 (padded for alignment)
    int* wptr    = rowptr + NN + 4;          // NN
    int* cnt     = wptr + NN;                // NN
    int* bsum    = cnt + NN;                 // 128 (scan block totals)
    int* ssrc    = bsum + 128;               // NE
    unsigned short* wcb  = (unsigned short*)(ssrc + NE); // 4*49152 bf16 frags
    unsigned short* whhb = wcb + 4 * 49152;              // 4*49152 bf16 frags
    unsigned short* nfb  = whhb + 4 * 49152;             // NNP*96 bf16 padded nf
    unsigned short* web  = nfb + (size_t)NNP * 96;       // 12288 emb B-frags

    // ---- once-per-call precompute: weights (+bf16 frags), nf cast, CSR ----
    k_wc<<<4 * 384, 128, 0, stream>>>(Wih, msgW, msgb, Wc, bmih);
    k_frag<<<8 * 192, 256, 0, stream>>>(Wc, Whh, wcb, whhb);
    k_nfb<<<(NN * 24 + 255) / 256, 256, 0, stream>>>(nf, nfb);
    k_wfrag_emb<<<48, 256, 0, stream>>>(embW, web);
    hipMemsetAsync(cnt, 0, NN * sizeof(int), stream);
    hipMemsetAsync(bnsum, 0, 5 * 256 * sizeof(double), stream);
    k_count<<<(NE + 255) / 256, 256, 0, stream>>>(dst, cnt);
    k_scan1<<<SCAN_G, SCAN_B, 0, stream>>>(cnt, rowptr, bsum);
    k_scan2<<<1, 128, 0, stream>>>(bsum, rowptr);
    k_scan3<<<SCAN_G, SCAN_B, 0, stream>>>(rowptr, bsum, wptr);
    k_scatter<<<(NE + 255) / 256, 256, 0, stream>>>(src, dst, wptr, ssrc);

    // ---- MFMA embedding (BN sums -> slot 0) + fused BN/att-proj ----
    k_embed_m<<<NB128, 256, 0, stream>>>(nfb, web, embb, y, bnsum);
    k_bnx<<<NN / 4, 256, 0, stream>>>(y, bnsum, embg, embbe, attW, xb, as_, ad_);

    for (int l = 0; l < NLAYERS; l++) {
        k_gather<<<NN / 8, 256, 0, stream>>>(rowptr, ssrc, xb, as_, ad_, attb, l, aggxb, sumatt);
        k_gru<<<NB128, 256, 0, stream>>>(
            aggxb, sumatt, xb,
            wcb + (size_t)l * 49152, bmih + (size_t)l * 384, bih + (size_t)l * 384,
            whhb + (size_t)l * 49152, bhh + (size_t)l * 384, y, bnsum + (l + 1) * 256);
        const float* attW_next = attW + (size_t)((l + 1 < NLAYERS) ? l + 1 : l) * 256;
        k_bnx<<<NN / 4, 256, 0, stream>>>(y, bnsum + (l + 1) * 256,
                                          bng + (size_t)l * HID, bnb + (size_t)l * HID,
                                          attW_next, xb, as_, ad_);
    }

    hipMemsetAsync(gr, 0, NGRAPHS * HID * sizeof(float), stream);
    k_pool<<<(NN + 255) / 256, 256, 0, stream>>>(xb, batch, gr);
    k_readout<<<NGRAPHS, 64, 0, stream>>>(gr, roW1, rob1, roW2, rob2, out);
}

// Round 5
// 614.391 us; speedup vs baseline: 1.0936x; 1.0936x over previous
//
#include <hip/hip_runtime.h>
#include <math.h>

#define NN 50000
#define NE 600000
#define ADIM 75
#define HID 128
#define NLAYERS 4
#define NGRAPHS 128
#define BN_EPS 1e-5f
#define NNP 50048   // NN padded to 128-node blocks (50048 = 391*128)
#define NB128 (NNP / 128)   // 391 node-blocks

typedef short bhalf8 __attribute__((ext_vector_type(8)));
typedef float floatx4 __attribute__((ext_vector_type(4)));

__device__ __forceinline__ float sigm(float v) { return 1.0f / (1.0f + __expf(-v)); }
__device__ __forceinline__ float tanh_f(float v) {
    return 1.0f - 2.0f / (__expf(2.0f * v) + 1.0f);
}

// fp32 -> bf16 with round-to-nearest-even
__device__ __forceinline__ unsigned short f2bf(float f) {
    unsigned u = __builtin_bit_cast(unsigned, f);
    u = (u + 0x7FFFu + ((u >> 16) & 1u)) >> 16;
    return (unsigned short)u;
}
__device__ __forceinline__ float bf2f(unsigned short h) {
    return __builtin_bit_cast(float, ((unsigned)h) << 16);
}

// async global->LDS, 16B per lane. LDS dest is wave-uniform base + lane*16;
// global src is per-lane (must already include +lane*16).
__device__ __forceinline__ void gl2lds16(const void* g, void* l) {
    __builtin_amdgcn_global_load_lds(
        (const __attribute__((address_space(1))) unsigned int*)g,
        (__attribute__((address_space(3))) unsigned int*)l, 16, 0, 0);
}

// ---------------------------------------------------------------------------
// nf [NN x 75] fp32 -> nfb [NNP x 96] bf16 (K zero-padded 75->96)
// ---------------------------------------------------------------------------
__global__ __launch_bounds__(256) void k_nfb(
    const float* __restrict__ nf, unsigned short* __restrict__ nfb)
{
    int e = blockIdx.x * 256 + threadIdx.x;      // (n, k4): 50000*24
    if (e >= NN * 24) return;
    int n = e / 24, k4 = e - n * 24;
    ushort4 o;
    int k = k4 * 4;
    o.x = (k + 0 < ADIM) ? f2bf(nf[(size_t)n * ADIM + k + 0]) : 0;
    o.y = (k + 1 < ADIM) ? f2bf(nf[(size_t)n * ADIM + k + 1]) : 0;
    o.z = (k + 2 < ADIM) ? f2bf(nf[(size_t)n * ADIM + k + 2]) : 0;
    o.w = (k + 3 < ADIM) ? f2bf(nf[(size_t)n * ADIM + k + 3]) : 0;
    ((ushort4*)nfb)[(size_t)n * 24 + k4] = o;
}

// ---------------------------------------------------------------------------
// embW [128 x 75] -> bf16 B-fragments, K padded to 96:
//   layout [tc(8)][kb(3)][quad(4)][n(16)][j(8)], elem = W[tc*16+n][kb*32+quad*8+j]
// ---------------------------------------------------------------------------
__global__ __launch_bounds__(256) void k_wfrag_emb(
    const float* __restrict__ W, unsigned short* __restrict__ web)
{
    int e = blockIdx.x * 256 + threadIdx.x;      // 0..12287
    int j = e & 7, n = (e >> 3) & 15, quad = (e >> 7) & 3;
    int kb = (e >> 9) % 3, tc = e / 1536;
    int row = tc * 16 + n;
    int kk = kb * 32 + quad * 8 + j;
    web[e] = (kk < ADIM) ? f2bf(W[row * ADIM + kk]) : 0;
}

// ---------------------------------------------------------------------------
// MFMA embedding — R20: 512 threads (8 waves), 128 nodes/block, grid 391.
// Per-wave code identical to R18 (16-node tile, same registers); the 24 KB
// weight stage now feeds 8 waves. R19 lesson: reuse via MORE WAVES, never
// more tiles per wave (register doubling -> 168 VGPR + scratch, 2.4x slower).
// ---------------------------------------------------------------------------
__global__ __launch_bounds__(512) void k_embed_m(
    const unsigned short* __restrict__ nfb, const unsigned short* __restrict__ web,
    const float* __restrict__ b, float* __restrict__ y,
    float* __restrict__ bnsum)
{
    __shared__ __align__(16) unsigned short wbe[12288];    // 24 KB emb B-frags
    __shared__ float sred[1024], sred2[1024];              // 8 KB BN partials
    const int t = threadIdx.x;
    const int wave = t >> 6, lane = t & 63;
    const int col = lane & 15, quad = (lane >> 4) & 3;
    const int node0 = blockIdx.x * 128;

    // stage web: 24576 B = 8 waves x 3 KB, identity copy
    {
        const char* gsrc = (const char*)web + wave * 3072 + lane * 16;
        char* ldst = (char*)wbe + wave * 3072;
#pragma unroll
        for (int i = 0; i < 3; i++)
            gl2lds16(gsrc + i * 1024, ldst + i * 1024);
    }

    const int anode = node0 + wave * 16 + col;
    bhalf8 afN[3];
#pragma unroll
    for (int kb = 0; kb < 3; kb++)
        afN[kb] = *(const bhalf8*)&nfb[(size_t)anode * 96 + kb * 32 + quad * 8];

    floatx4 acc[8];
#pragma unroll
    for (int tc = 0; tc < 8; tc++) {
        float bv = b[tc * 16 + col];
        acc[tc] = (floatx4){bv, bv, bv, bv};
    }
    __syncthreads();   // drains vmcnt -> wbe staged

#pragma unroll
    for (int tc = 0; tc < 8; tc++) {
        bhalf8 bfr[3];
#pragma unroll
        for (int kb = 0; kb < 3; kb++)
            bfr[kb] = *(const bhalf8*)&wbe[((tc * 3 + kb) * 64 + lane) * 8];
#pragma unroll
        for (int kb = 0; kb < 3; kb++)
            acc[tc] = __builtin_amdgcn_mfma_f32_16x16x32_bf16(afN[kb], bfr[kb], acc[tc], 0, 0, 0);
    }

    // relu + direct y stores + register BN partials
    float ps[8], ps2[8];
#pragma unroll
    for (int tc = 0; tc < 8; tc++) {
        ps[tc] = 0.f; ps2[tc] = 0.f;
#pragma unroll
        for (int e = 0; e < 4; e++) {
            float v = fmaxf(acc[tc][e], 0.0f);
            int nd = node0 + wave * 16 + quad * 4 + e;
            if (nd < NN) {
                y[(size_t)nd * HID + tc * 16 + col] = v;
                ps[tc] += v; ps2[tc] += v * v;
            }
        }
    }
#pragma unroll
    for (int tc = 0; tc < 8; tc++) {
        ps[tc]  += __shfl_xor(ps[tc], 16);  ps2[tc] += __shfl_xor(ps2[tc], 16);
        ps[tc]  += __shfl_xor(ps[tc], 32);  ps2[tc] += __shfl_xor(ps2[tc], 32);
    }
    if (quad == 0) {
#pragma unroll
        for (int tc = 0; tc < 8; tc++) {
            sred[wave * 128 + tc * 16 + col]  = ps[tc];
            sred2[wave * 128 + tc * 16 + col] = ps2[tc];
        }
    }
    __syncthreads();
    if (t < 128) {
        float s = 0.f, s2 = 0.f;
#pragma unroll
        for (int w = 0; w < 8; w++) { s += sred[w * 128 + t]; s2 += sred2[w * 128 + t]; }
        unsafeAtomicAdd(&bnsum[t], s);
        unsafeAtomicAdd(&bnsum[128 + t], s2);
    }
}

// ---------------------------------------------------------------------------
// Fused BN-finalize + BN-apply + bf16 mirror + attention projections.
// R20: bnsum is f32 now (f32 atomics are native fire-and-forget L2 adds).
// ---------------------------------------------------------------------------
__global__ __launch_bounds__(256) void k_bnx(
    const float* __restrict__ y, const float* __restrict__ bnsum,
    const float* __restrict__ g, const float* __restrict__ beta,
    const float* __restrict__ attW,
    unsigned short* __restrict__ xb,
    float* __restrict__ as_, float* __restrict__ ad_)
{
    const int t = threadIdx.x;
    const int n = blockIdx.x * 4 + (t >> 6);
    const int lane = t & 63;
    const int f0 = lane * 2;
    // per-thread BN scale/shift for features f0, f0+1
    float m0 = bnsum[f0] * (1.0f / NN);
    float v0 = bnsum[128 + f0] * (1.0f / NN) - m0 * m0;
    float m1 = bnsum[f0 + 1] * (1.0f / NN);
    float v1 = bnsum[128 + f0 + 1] * (1.0f / NN) - m1 * m1;
    float sc0 = g[f0] * rsqrtf(v0 + BN_EPS);
    float sc1 = g[f0 + 1] * rsqrtf(v1 + BN_EPS);
    float sh0 = beta[f0] - m0 * sc0;
    float sh1 = beta[f0 + 1] - m1 * sc1;

    float2 v = ((const float2*)y)[(size_t)n * 64 + lane];
    float2 xv;
    xv.x = v.x * sc0 + sh0;
    xv.y = v.y * sc1 + sh1;
    unsigned pk = (unsigned)f2bf(xv.x) | ((unsigned)f2bf(xv.y) << 16);
    ((unsigned*)xb)[(size_t)n * 64 + lane] = pk;
    float2 aws = ((const float2*)attW)[lane];
    float2 awd = ((const float2*)(attW + 128))[lane];
    float pas = xv.x * aws.x + xv.y * aws.y;
    float pad = xv.x * awd.x + xv.y * awd.y;
#pragma unroll
    for (int msk = 32; msk >= 1; msk >>= 1) {
        pas += __shfl_xor(pas, msk);
        pad += __shfl_xor(pad, msk);
    }
    if (lane == 0) { as_[n] = pas; ad_[n] = pad; }
}

// ---------------------------------------------------------------------------
// Combined-weight precompute: Wc[l] = Wih[l] @ Wm[l], bmih[l] = Wih[l] @ bm[l]
// ---------------------------------------------------------------------------
__global__ __launch_bounds__(128) void k_wc(
    const float* __restrict__ Wih, const float* __restrict__ Wm,
    const float* __restrict__ bm, float* __restrict__ Wc, float* __restrict__ bmih)
{
    __shared__ float sw[128];
    __shared__ float red[128];
    const int b = blockIdx.x;
    const int l = b / 384, r = b - l * 384;
    const int t = threadIdx.x;
    const float* wihrow = Wih + ((size_t)l * 384 + r) * 128;
    sw[t] = wihrow[t];
    __syncthreads();
    const float* wm = Wm + (size_t)l * 128 * 128;
    float acc = 0.f;
#pragma unroll 8
    for (int k = 0; k < 128; k++) acc += sw[k] * wm[k * 128 + t];
    Wc[((size_t)l * 384 + r) * 128 + t] = acc;
    red[t] = sw[t] * bm[l * 128 + t];
    __syncthreads();
#pragma unroll
    for (int off = 64; off >= 1; off >>= 1) {
        if (t < off) red[t] += red[t + off];
        __syncthreads();
    }
    if (t == 0) bmih[l * 384 + r] = red[0];
}

// ---------------------------------------------------------------------------
// Convert Wc (fp32) and Whh to bf16 in MFMA B-fragment order:
//   layout [gate(3)][tc(8)][kb(4)][quad(4)][n(16)][j(8)] per layer-matrix
// ---------------------------------------------------------------------------
__global__ __launch_bounds__(256) void k_frag(
    const float* __restrict__ Wc, const float* __restrict__ Whh,
    unsigned short* __restrict__ wcb, unsigned short* __restrict__ whhb)
{
    const int b = blockIdx.x;
    const int mat = b / 192;
    const int e = (b - mat * 192) * 256 + threadIdx.x;   // 0..49151
    const int l = mat >> 1, which = mat & 1;
    const float* src = which ? (Whh + (size_t)l * 49152) : (Wc + (size_t)l * 49152);
    unsigned short* dst = which ? (whhb + (size_t)l * 49152) : (wcb + (size_t)l * 49152);
    int j = e & 7, n = (e >> 3) & 15, quad = (e >> 7) & 3;
    int kb = (e >> 9) & 3, tc = (e >> 11) & 7, g = (e >> 14) & 3;
    int row = g * 128 + tc * 16 + n;
    int kk = kb * 32 + quad * 8 + j;
    dst[e] = f2bf(src[row * 128 + kk]);
}

// ---------------------------------------------------------------------------
// CSR build: histogram, 3-kernel device-wide scan, scatter
// ---------------------------------------------------------------------------
__global__ __launch_bounds__(256) void k_count(const int* __restrict__ dst, int* __restrict__ cnt)
{
    int e = blockIdx.x * 256 + threadIdx.x;
    if (e < NE) atomicAdd(&cnt[dst[e]], 1);
}

#define SCAN_B 512
#define SCAN_G 98          // 98*512 = 50176 >= 50000

__global__ __launch_bounds__(SCAN_B) void k_scan1(
    const int* __restrict__ cnt, int* __restrict__ rowptr, int* __restrict__ bsum)
{
    __shared__ int s[SCAN_B];
    const int t = threadIdx.x;
    const int i = blockIdx.x * SCAN_B + t;
    int v = (i < NN) ? cnt[i] : 0;
    s[t] = v;
    __syncthreads();
#pragma unroll
    for (int off = 1; off < SCAN_B; off <<= 1) {
        int u = (t >= off) ? s[t - off] : 0;
        __syncthreads();
        s[t] += u;
        __syncthreads();
    }
    if (i < NN) rowptr[i] = s[t] - v;        // local exclusive
    if (t == SCAN_B - 1) bsum[blockIdx.x] = s[t];
}

__global__ __launch_bounds__(128) void k_scan2(int* __restrict__ bsum, int* __restrict__ rowptr)
{
    __shared__ int s[128];
    const int t = threadIdx.x;
    int v = (t < SCAN_G) ? bsum[t] : 0;
    s[t] = v;
    __syncthreads();
#pragma unroll
    for (int off = 1; off < 128; off <<= 1) {
        int u = (t >= off) ? s[t - off] : 0;
        __syncthreads();
        s[t] += u;
        __syncthreads();
    }
    if (t < SCAN_G) bsum[t] = s[t] - v;      // exclusive offsets
    if (t == 127) rowptr[NN] = s[127];       // grand total (= NE)
}

__global__ __launch_bounds__(SCAN_B) void k_scan3(
    int* __restrict__ rowptr, const int* __restrict__ bsum, int* __restrict__ wptr)
{
    const int i = blockIdx.x * SCAN_B + threadIdx.x;
    if (i < NN) {
        int v = rowptr[i] + bsum[blockIdx.x];
        rowptr[i] = v;
        wptr[i] = v;
    }
}

__global__ __launch_bounds__(256) void k_scatter(
    const int* __restrict__ src, const int* __restrict__ dst,
    int* __restrict__ wptr, int* __restrict__ ssrc)
{
    int e = blockIdx.x * 256 + threadIdx.x;
    if (e < NE) {
        int d = dst[e];
        int pos = atomicAdd(&wptr[d], 1);
        ssrc[pos] = src[e];
    }
}

// ---------------------------------------------------------------------------
// Gather-aggregate, batched + id-PIPELINED. block 256 = 8 nodes x 32 lanes.
// ---------------------------------------------------------------------------
__global__ __launch_bounds__(256) void k_gather(
    const int* __restrict__ rowptr, const int* __restrict__ ssrc,
    const unsigned short* __restrict__ xb, const float* __restrict__ as_,
    const float* __restrict__ ad_, const float* __restrict__ attb, int l,
    unsigned short* __restrict__ aggxb, float* __restrict__ sumatt)
{
    const int t = threadIdx.x;
    const int n = blockIdx.x * 8 + (t >> 5);
    const int lane = t & 31;
    const int r0 = rowptr[n], r1 = rowptr[n + 1];
    const float adv = ad_[n] + attb[l];
    float4 acc = make_float4(0.f, 0.f, 0.f, 0.f);
    float satt = 0.f;

    int ids[8], ids2[8];
    if (r0 < r1) {
#pragma unroll
        for (int k = 0; k < 8; k++) {
            int idx = r0 + k; if (idx >= r1) idx = r1 - 1;
            ids[k] = ssrc[idx];
        }
    }
    for (int base = r0; base < r1; base += 8) {
        const int nxt = base + 8;
        if (nxt < r1) {
#pragma unroll
            for (int k = 0; k < 8; k++) {
                int idx = nxt + k; if (idx >= r1) idx = r1 - 1;
                ids2[k] = ssrc[idx];
            }
        }
        ushort4 v[8];
        float a[8];
#pragma unroll
        for (int k = 0; k < 8; k++) {
            v[k] = ((const ushort4*)xb)[(size_t)ids[k] * 32 + lane];
            a[k] = as_[ids[k]];
        }
#pragma unroll
        for (int k = 0; k < 8; k++) {
            if (base + k < r1) {
                float att = sigm(a[k] + adv);
                acc.x += bf2f(v[k].x) * att; acc.y += bf2f(v[k].y) * att;
                acc.z += bf2f(v[k].z) * att; acc.w += bf2f(v[k].w) * att;
                satt += att;
            }
        }
#pragma unroll
        for (int k = 0; k < 8; k++) ids[k] = ids2[k];
    }
    ushort4 o;
    o.x = f2bf(acc.x); o.y = f2bf(acc.y); o.z = f2bf(acc.z); o.w = f2bf(acc.w);
    ((ushort4*)aggxb)[(size_t)n * 32 + lane] = o;
    if (lane == 0) sumatt[n] = satt;
}

// ---------------------------------------------------------------------------
// MFMA GRU — R20: 512 threads (8 waves), 128 nodes/block, grid 391.
// R19 lesson: weight-stage reuse must come from MORE WAVES per block, not
// more node-tiles per wave (register doubling -> 168 VGPR + scratch spills,
// 2.4x slower). Here per-wave code is IDENTICAL to R18 (96 VGPR, 16-node
// tile); each 32 KB stage feeds 8 waves -> stage drains per node halved,
// weight L2 traffic halved, grid 391 fully co-resident (~2 blocks/CU by
// VGPR, 4 by LDS=40KB) in one round.
// R11/R13: do NOT force occupancy via launch_bounds/waves_per_eu.
// R8: do NOT split this grid along columns — A-traffic multiplies.
// ---------------------------------------------------------------------------
#define STAGE_W(SRC)                                                          \
    {                                                                         \
        const char* gsrc = (const char*)(SRC) + wave * 4096 + lane * 16;      \
        char* ldst = (char*)wbuf + wave * 4096;                               \
        _Pragma("unroll")                                                     \
        for (int i = 0; i < 4; i++)                                           \
            gl2lds16(gsrc + i * 1024, ldst + i * 1024);                       \
    }

#define MMGL(AF, ACC)                                                         \
    _Pragma("unroll")                                                         \
    for (int tc = 0; tc < 8; tc++) {                                          \
        bhalf8 bfr[4];                                                        \
        _Pragma("unroll")                                                     \
        for (int kb = 0; kb < 4; kb++)                                        \
            bfr[kb] = *(const bhalf8*)&wbuf[((tc * 4 + kb) * 64 + lane) * 8]; \
        _Pragma("unroll")                                                     \
        for (int kb = 0; kb < 4; kb++)                                        \
            ACC[tc] = __builtin_amdgcn_mfma_f32_16x16x32_bf16(AF[kb], bfr[kb], ACC[tc], 0, 0, 0); \
    }

__global__ __launch_bounds__(512) void k_gru(
    const unsigned short* __restrict__ aggxb, const float* __restrict__ sumatt,
    const unsigned short* __restrict__ xb,
    const unsigned short* __restrict__ wcb, const float* __restrict__ bmih,
    const float* __restrict__ bih,
    const unsigned short* __restrict__ whhb, const float* __restrict__ bhh,
    float* __restrict__ y, float* __restrict__ bnsum)
{
    __shared__ __align__(16) unsigned short wbuf[16384];   // 32 KB weight stage
    __shared__ float sred[1024], sred2[1024];              // 8 KB BN partials
    const int t = threadIdx.x;
    const int wave = t >> 6, lane = t & 63;
    const int col = lane & 15, quad = (lane >> 4) & 3;
    const int node0 = blockIdx.x * 128;

    STAGE_W(wcb + 0 * 16384);    // issue gate-r Wc stage before A loads

    const int anode = node0 + wave * 16 + col;
    bhalf8 afA[4], afX[4];
#pragma unroll
    for (int kb = 0; kb < 4; kb++) {
        afA[kb] = *(const bhalf8*)&aggxb[(size_t)anode * HID + kb * 32 + quad * 8];
        afX[kb] = *(const bhalf8*)&xb[(size_t)anode * HID + kb * 32 + quad * 8];
    }
    float sa[4];
#pragma unroll
    for (int e = 0; e < 4; e++) sa[e] = sumatt[node0 + wave * 16 + quad * 4 + e];

    floatx4 accR[8], accN[8];

    // ===== gate r: merged accumulator (gi+gh) =====
#pragma unroll
    for (int tc = 0; tc < 8; tc++) {
        int f = 0 * 128 + tc * 16 + col;
        float b0 = bih[f] + bhh[f], bm = bmih[f];
        accR[tc] = (floatx4){b0 + sa[0] * bm, b0 + sa[1] * bm, b0 + sa[2] * bm, b0 + sa[3] * bm};
    }
    __syncthreads();                 // wcb[r] staged (drains vmcnt)
    MMGL(afA, accR);
    __syncthreads();                 // all waves done reading
    STAGE_W(whhb + 0 * 16384);
    __syncthreads();
    MMGL(afX, accR);
    __syncthreads();
    STAGE_W(whhb + 2 * 16384);       // prefetch gate-n Whh; sigm overlaps
#pragma unroll
    for (int tc = 0; tc < 8; tc++)
#pragma unroll
        for (int e = 0; e < 4; e++)
            accR[tc][e] = sigm(accR[tc][e]);          // accR now holds r

    // ===== gate n: acc = afX@Whh + bh; acc = r*acc + bi + sa*bm; acc += afA@Wc =====
#pragma unroll
    for (int tc = 0; tc < 8; tc++) {
        float bh = bhh[2 * 128 + tc * 16 + col];
        accN[tc] = (floatx4){bh, bh, bh, bh};
    }
    __syncthreads();
    MMGL(afX, accN);
    __syncthreads();
    STAGE_W(wcb + 2 * 16384);        // prefetch gate-n Wc; r-merge overlaps
#pragma unroll
    for (int tc = 0; tc < 8; tc++) {
        int f = 2 * 128 + tc * 16 + col;
        float bi = bih[f], bm = bmih[f];
#pragma unroll
        for (int e = 0; e < 4; e++)
            accN[tc][e] = accR[tc][e] * accN[tc][e] + bi + sa[e] * bm;
    }
    __syncthreads();
    MMGL(afA, accN);
    __syncthreads();
    STAGE_W(wcb + 1 * 16384);        // prefetch gate-z Wc; tanh overlaps
#pragma unroll
    for (int tc = 0; tc < 8; tc++)
#pragma unroll
        for (int e = 0; e < 4; e++)
            accN[tc][e] = tanh_f(accN[tc][e]);        // accN now holds n

    // ===== gate z: merged accumulator (reuse accR) =====
#pragma unroll
    for (int tc = 0; tc < 8; tc++) {
        int f = 1 * 128 + tc * 16 + col;
        float b0 = bih[f] + bhh[f], bm = bmih[f];
        accR[tc] = (floatx4){b0 + sa[0] * bm, b0 + sa[1] * bm, b0 + sa[2] * bm, b0 + sa[3] * bm};
    }
    __syncthreads();
    MMGL(afA, accR);
    __syncthreads();
    STAGE_W(whhb + 1 * 16384);
    __syncthreads();
    MMGL(afX, accR);

    // ===== h = (1-z)*n + z*x; direct y stores; register BN partials =====
    float ps[8], ps2[8];
#pragma unroll
    for (int tc = 0; tc < 8; tc++) {
        ps[tc] = 0.f; ps2[tc] = 0.f;
#pragma unroll
        for (int e = 0; e < 4; e++) {
            float z = sigm(accR[tc][e]);
            int nd = node0 + wave * 16 + quad * 4 + e;
            float xv = bf2f(xb[(size_t)nd * HID + tc * 16 + col]);
            float h = (1.0f - z) * accN[tc][e] + z * xv;
            if (nd < NN) {
                y[(size_t)nd * HID + tc * 16 + col] = h;
                ps[tc] += h; ps2[tc] += h * h;
            }
        }
    }
#pragma unroll
    for (int tc = 0; tc < 8; tc++) {
        ps[tc]  += __shfl_xor(ps[tc], 16);  ps2[tc] += __shfl_xor(ps2[tc], 16);
        ps[tc]  += __shfl_xor(ps[tc], 32);  ps2[tc] += __shfl_xor(ps2[tc], 32);
    }
    if (quad == 0) {
#pragma unroll
        for (int tc = 0; tc < 8; tc++) {
            sred[wave * 128 + tc * 16 + col]  = ps[tc];
            sred2[wave * 128 + tc * 16 + col] = ps2[tc];
        }
    }
    __syncthreads();
    if (t < 128) {
        float s = 0.f, s2 = 0.f;
#pragma unroll
        for (int w = 0; w < 8; w++) { s += sred[w * 128 + t]; s2 += sred2[w * 128 + t]; }
        unsafeAtomicAdd(&bnsum[t], s);
        unsafeAtomicAdd(&bnsum[128 + t], s2);
    }
}

// ---------------------------------------------------------------------------
// Segmented sum-pool over bf16 xb (batch_idx is SORTED)
// ---------------------------------------------------------------------------
__global__ __launch_bounds__(256) void k_pool(
    const unsigned short* __restrict__ xb, const int* __restrict__ batch,
    float* __restrict__ gr)
{
    __shared__ int sb[256];
    const int t = threadIdx.x;
    const int nb = blockIdx.x * 256;
    int ld = nb + t; if (ld >= NN) ld = NN - 1;
    sb[t] = batch[ld];
    __syncthreads();
    const int s = t >> 7, f = t & 127;
    float acc = 0.f; int cur = -1;
    for (int i = s; i < 256; i += 2) {
        int n = nb + i;
        if (n >= NN) break;
        int g = sb[i];
        if (g != cur) {
            if (cur >= 0) unsafeAtomicAdd(&gr[(size_t)cur * HID + f], acc);
            acc = 0.f; cur = g;
        }
        acc += bf2f(xb[(size_t)n * HID + f]);
    }
    if (cur >= 0) unsafeAtomicAdd(&gr[(size_t)cur * HID + f], acc);
}

// ---------------------------------------------------------------------------
// Readout: out[g] = relu(gr[g] @ W1^T + b1) @ W2^T + b2   (128 blocks x 64)
// ---------------------------------------------------------------------------
__global__ __launch_bounds__(64) void k_readout(
    const float* __restrict__ gr, const float* __restrict__ W1,
    const float* __restrict__ b1, const float* __restrict__ W2,
    const float* __restrict__ b2, float* __restrict__ out)
{
    const int g = blockIdx.x, j = threadIdx.x;
    float acc = b1[j];
    const float4* grow = (const float4*)&gr[g * HID];
    const float4* wrow = (const float4*)&W1[j * HID];
#pragma unroll
    for (int k4 = 0; k4 < 32; k4++) {
        float4 a = grow[k4], w = wrow[k4];
        acc += a.x * w.x + a.y * w.y + a.z * w.z + a.w * w.w;
    }
    float h = fmaxf(acc, 0.0f) * W2[j];
#pragma unroll
    for (int msk = 32; msk >= 1; msk >>= 1) h += __shfl_xor(h, msk);
    if (j == 0) out[g] = h + b2[0];
}

// ---------------------------------------------------------------------------
extern "C" void kernel_launch(void* const* d_in, const int* in_sizes, int n_in,
                              void* d_out, int out_size, void* d_ws, size_t ws_size,
                              hipStream_t stream)
{
    const float* nf    = (const float*)d_in[0];
    const int*   ei    = (const int*)d_in[1];
    const int*   batch = (const int*)d_in[2];
    const float* embW  = (const float*)d_in[3];
    const float* embb  = (const float*)d_in[4];
    const float* embg  = (const float*)d_in[5];
    const float* embbe = (const float*)d_in[6];
    const float* msgW  = (const float*)d_in[7];
    const float* msgb  = (const float*)d_in[8];
    const float* attW  = (const float*)d_in[9];
    const float* attb  = (const float*)d_in[10];
    const float* Wih   = (const float*)d_in[11];
    const float* bih   = (const float*)d_in[12];
    const float* Whh   = (const float*)d_in[13];
    const float* bhh   = (const float*)d_in[14];
    const float* bng   = (const float*)d_in[15];
    const float* bnb   = (const float*)d_in[16];
    const float* roW1  = (const float*)d_in[17];
    const float* rob1  = (const float*)d_in[18];
    const float* roW2  = (const float*)d_in[19];
    const float* rob2  = (const float*)d_in[20];
    const int* src = ei;
    const int* dst = ei + NE;
    float* out = (float*)d_out;

    // ---- workspace layout (all sections 16B-multiple) ----
    char* base = (char*)d_ws;
    const size_t NH = (size_t)NN * HID;      // 6.4M elements
    float* bnsum = (float*)base;             // 5 slots x 256 floats (10240 B reserved)
    float* y     = (float*)(base + 10240);   // pre-BN state
    unsigned short* xb    = (unsigned short*)(y + NH);   // bf16 node state
    unsigned short* aggxb = xb + NH;                     // bf16 gather output
    float* as_   = (float*)(aggxb + NH);
    float* ad_   = as_ + NN;
    float* sumatt= ad_ + NN;
    float* gr    = sumatt + NN;              // 128*128
    float* Wc    = gr + NGRAPHS * HID;       // 4*384*128 fp32
    float* bmih  = Wc + 4 * 384 * 128;       // 4*384
    int* rowptr  = (int*)(bmih + 4 * 384);   // NN+4 (padded for alignment)
    int* wptr    = rowptr + NN + 4;          // NN
    int* cnt     = wptr + NN;                // NN
    int* bsum    = cnt + NN;                 // 128 (scan block totals)
    int* ssrc    = bsum + 128;               // NE
    unsigned short* wcb  = (unsigned short*)(ssrc + NE); // 4*49152 bf16 frags
    unsigned short* whhb = wcb + 4 * 49152;              // 4*49152 bf16 frags
    unsigned short* nfb  = whhb + 4 * 49152;             // NNP*96 bf16 padded nf
    unsigned short* web  = nfb + (size_t)NNP * 96;       // 12288 emb B-frags

    // ---- once-per-call precompute: weights (+bf16 frags), nf cast, CSR ----
    k_wc<<<4 * 384, 128, 0, stream>>>(Wih, msgW, msgb, Wc, bmih);
    k_frag<<<8 * 192, 256, 0, stream>>>(Wc, Whh, wcb, whhb);
    k_nfb<<<(NN * 24 + 255) / 256, 256, 0, stream>>>(nf, nfb);
    k_wfrag_emb<<<48, 256, 0, stream>>>(embW, web);
    hipMemsetAsync(cnt, 0, NN * sizeof(int), stream);
    hipMemsetAsync(bnsum, 0, 5 * 256 * sizeof(float), stream);
    k_count<<<(NE + 255) / 256, 256, 0, stream>>>(dst, cnt);
    k_scan1<<<SCAN_G, SCAN_B, 0, stream>>>(cnt, rowptr, bsum);
    k_scan2<<<1, 128, 0, stream>>>(bsum, rowptr);
    k_scan3<<<SCAN_G, SCAN_B, 0, stream>>>(rowptr, bsum, wptr);
    k_scatter<<<(NE + 255) / 256, 256, 0, stream>>>(src, dst, wptr, ssrc);

    // ---- MFMA embedding (BN sums -> slot 0) + fused BN/att-proj ----
    k_embed_m<<<NB128, 512, 0, stream>>>(nfb, web, embb, y, bnsum);
    k_bnx<<<NN / 4, 256, 0, stream>>>(y, bnsum, embg, embbe, attW, xb, as_, ad_);

    for (int l = 0; l < NLAYERS; l++) {
        k_gather<<<NN / 8, 256, 0, stream>>>(rowptr, ssrc, xb, as_, ad_, attb, l, aggxb, sumatt);
        k_gru<<<NB128, 512, 0, stream>>>(
            aggxb, sumatt, xb,
            wcb + (size_t)l * 49152, bmih + (size_t)l * 384, bih + (size_t)l * 384,
            whhb + (size_t)l * 49152, bhh + (size_t)l * 384, y, bnsum + (l + 1) * 256);
        const float* attW_next = attW + (size_t)((l + 1 < NLAYERS) ? l + 1 : l) * 256;
        k_bnx<<<NN / 4, 256, 0, stream>>>(y, bnsum + (l + 1) * 256,
                                          bng + (size_t)l * HID, bnb + (size_t)l * HID,
                                          attW_next, xb, as_, ad_);
    }

    hipMemsetAsync(gr, 0, NGRAPHS * HID * sizeof(float), stream);
    k_pool<<<(NN + 255) / 256, 256, 0, stream>>>(xb, batch, gr);
    k_readout<<<NGRAPHS, 64, 0, stream>>>(gr, roW1, rob1, roW2, rob2, out);
}